// Round 4
// baseline (26126.236 us; speedup 1.0000x reference)
//
#include <hip/hip_runtime.h>
#include <hip/hip_bf16.h>
#include <math.h>

// ---------------- problem constants ----------------
#define S_LEN 2048
#define T_LEN 2048
#define HID   1024
#define GATES 4096          // 4*HID
#define VOCAB 50257
#define NWG2  192           // fused kernel: 64 L0 WGs + 128 L1 WGs
#define RECT  512           // threads per rec workgroup

typedef unsigned int u32;

__device__ __forceinline__ float fsig_(float x)  { return 1.0f / (1.0f + __expf(-x)); }
__device__ __forceinline__ float ftanh_(float x) { float e = __expf(2.0f * x); return 1.0f - 2.0f / (e + 1.0f); }

// coherent 16B read that bypasses the (non-coherent, per-XCD) L1/L2
__device__ __forceinline__ float4 load_coherent4(const float* p) {
  float4 v;
  asm volatile("global_load_dwordx4 %0, %1, off sc0 sc1\n\ts_waitcnt vmcnt(0)"
               : "=v"(v) : "v"(p) : "memory");
  return v;
}

// ---------------- tiny helpers ----------------
__global__ void zero_u32(u32* __restrict__ p, int n) {
  int i = blockIdx.x * blockDim.x + threadIdx.x;
  if (i < n) p[i] = 0u;
}

__global__ void build_dec_tokens(const int* __restrict__ outputs, const int* __restrict__ sos,
                                 int* __restrict__ toks, int T) {
  int t = blockIdx.x * blockDim.x + threadIdx.x;
  if (t < T) toks[t] = (t == 0) ? sos[0] : outputs[t - 1];
}

// one block per row; 256 threads copy 1024 floats as float4
__global__ void gather_rows(const float* __restrict__ emb, const int* __restrict__ toks,
                            float* __restrict__ out) {
  int row = blockIdx.x;
  int tok = toks[row];
  const float4* src = (const float4*)(emb + (size_t)tok * HID);
  float4* dst = (float4*)(out + (size_t)row * HID);
  dst[threadIdx.x] = src[threadIdx.x];
}

// ---------------- f32 GEMM: C[M][N] = X[M][K] @ W[N][K]^T + b1 + b2 ----------------
// 64x64 tile, 256 threads, 4x4 microtile, BK=16
__global__ __launch_bounds__(256) void gemm_xwt(
    const float* __restrict__ X, const float* __restrict__ W,
    const float* __restrict__ b1, const float* __restrict__ b2,
    float* __restrict__ C, int M, int N, int K)
{
  __shared__ float Xs[16][68];   // [k][m], padded
  __shared__ float Ws[16][68];   // [k][n]
  const int tid = threadIdx.x;
  const int tx = tid & 15;
  const int ty = tid >> 4;
  const int m0 = blockIdx.y * 64;
  const int n0 = blockIdx.x * 64;
  const int lr = tid >> 2;          // 0..63 tile row
  const int lc = (tid & 3) * 4;     // 0,4,8,12 k offset
  float acc[4][4] = {{0.f}};

  for (int k0 = 0; k0 < K; k0 += 16) {
    float4 xv = *(const float4*)(X + (size_t)(m0 + lr) * K + k0 + lc);
    float4 wv = make_float4(0.f, 0.f, 0.f, 0.f);
    int wr = n0 + lr;
    if (wr < N) wv = *(const float4*)(W + (size_t)wr * K + k0 + lc);
    __syncthreads();
    Xs[lc + 0][lr] = xv.x; Xs[lc + 1][lr] = xv.y; Xs[lc + 2][lr] = xv.z; Xs[lc + 3][lr] = xv.w;
    Ws[lc + 0][lr] = wv.x; Ws[lc + 1][lr] = wv.y; Ws[lc + 2][lr] = wv.z; Ws[lc + 3][lr] = wv.w;
    __syncthreads();
#pragma unroll
    for (int kk = 0; kk < 16; ++kk) {
      float4 a = *(const float4*)&Xs[kk][ty * 4];
      float4 b = *(const float4*)&Ws[kk][tx * 4];
      float av[4] = {a.x, a.y, a.z, a.w};
      float bv[4] = {b.x, b.y, b.z, b.w};
#pragma unroll
      for (int i = 0; i < 4; ++i)
#pragma unroll
        for (int j = 0; j < 4; ++j)
          acc[i][j] = fmaf(av[i], bv[j], acc[i][j]);
    }
  }
#pragma unroll
  for (int i = 0; i < 4; ++i) {
    int m = m0 + ty * 4 + i;
#pragma unroll
    for (int j = 0; j < 4; ++j) {
      int n = n0 + tx * 4 + j;
      if (n < N) {
        float bias = 0.f;
        if (b1) bias += b1[n];
        if (b2) bias += b2[n];
        C[(size_t)m * N + n] = acc[i][j] + bias;
      }
    }
  }
}

// ---------------- fused 2-layer persistent LSTM, layer-pipelined ----------------
// 192 WGs: wg<64 run layer 0 (A = Wi@x+bi+bh precomputed); wg>=64 run layer 1
// (Wi1@h0_t + Wh1@h1_{t-1} + biases fused, 1-step pipeline skew behind layer 0).
// Exchange protocol (write-once streams, zeroed tags each launch):
//   data: plain f32 stream [T][HID], PRODUCER writes via relaxed 4B agent atomics
//         (UC path -> reaches coherence point, never parked in a non-coherent L2);
//         CONSUMER reads via global_load_dwordx4 sc0 sc1 (coherent 16B read).
//   tags: one u32 per producer-WG per step, value t+1. Producer: data stores ->
//         s_waitcnt vmcnt(0) (UC store completion == global visibility) -> tag store.
//         Consumer thread polls only the tag covering its own 4 data floats.
// This cuts per-step fabric ops ~6x vs per-slot {tag,h} polling (R3 was
// fabric-throughput-bound: FETCH 335 MB/dispatch of poll traffic).
__global__ __launch_bounds__(RECT, 2) void lstm2(
    const float* __restrict__ A,   const float* __restrict__ Wh0,
    const float* __restrict__ Wi1, const float* __restrict__ Wh1,
    const float* __restrict__ bi1, const float* __restrict__ bh1,
    const float* __restrict__ h00, const float* __restrict__ c00,
    const float* __restrict__ h01, const float* __restrict__ c01,
    float* __restrict__ s0, float* __restrict__ s1,     // data streams [T][HID]
    u32* __restrict__ t0, u32* __restrict__ t1,         // tags [T][64] / [T][128]
    float* __restrict__ hf0, float* __restrict__ cf0,
    float* __restrict__ hf1, float* __restrict__ cf1,
    float* __restrict__ dec_out, int T)
{
  const int tid = threadIdx.x;
  const int wg = blockIdx.x;

  __shared__ float lds_x[HID];
  __shared__ float lds_h[HID];
  __shared__ float lds_g[64];
  __shared__ float lds_c[16];

  if (wg < 64) {
    // ================= layer 0: 16 units/WG, 8 lanes/row =================
    const int lane8 = tid & 7;
    const int rloc = tid >> 3;            // 0..63
    const int jloc = rloc & 15;
    const int gate = rloc >> 4;           // i,f,g,o
    const int grow = gate * HID + wg * 16 + jloc;

    float4 Wr[32];
    {
      const float4* wrow = (const float4*)(Wh0 + (size_t)grow * HID);
#pragma unroll
      for (int i = 0; i < 32; ++i) Wr[i] = wrow[lane8 + i * 8];
    }

    if (tid < 16) lds_c[tid] = c00[wg * 16 + tid];
    if (tid < 256) ((float4*)lds_h)[tid] = ((const float4*)h00)[tid];
    __syncthreads();

    float areg = (lane8 == 0) ? A[grow] : 0.f;    // step-0 preactivation

    for (int t = 0; t < T; ++t) {
      if (t > 0) {
        if (tid < 256) {
          const int c4 = tid << 2;
          const u32* tg = t0 + (size_t)(t - 1) * 64 + (c4 >> 4);
          while (__hip_atomic_load(tg, __ATOMIC_RELAXED, __HIP_MEMORY_SCOPE_AGENT) < (u32)t) {}
          const float4 v = load_coherent4(s0 + (size_t)(t - 1) * HID + c4);
          *(float4*)&lds_h[c4] = v;
        }
        __syncthreads();
      }

      const float aval = areg;
      if (lane8 == 0 && t + 1 < T) areg = A[(size_t)(t + 1) * GATES + grow];  // prefetch

      float p0 = 0.f, p1 = 0.f, p2 = 0.f, p3 = 0.f;
#pragma unroll
      for (int i = 0; i < 32; ++i) {
        const float4 hv = *(const float4*)&lds_h[(lane8 << 2) + (i << 5)];
        p0 = fmaf(Wr[i].x, hv.x, p0);
        p1 = fmaf(Wr[i].y, hv.y, p1);
        p2 = fmaf(Wr[i].z, hv.z, p2);
        p3 = fmaf(Wr[i].w, hv.w, p3);
      }
      float sum = (p0 + p1) + (p2 + p3);
      sum += __shfl_xor(sum, 1);
      sum += __shfl_xor(sum, 2);
      sum += __shfl_xor(sum, 4);
      if (lane8 == 0) lds_g[rloc] = sum + aval;
      __syncthreads();

      if (tid < 16) {
        const float gi = lds_g[tid];
        const float gf = lds_g[16 + tid];
        const float gg = lds_g[32 + tid];
        const float go = lds_g[48 + tid];
        const float c = fsig_(gf) * lds_c[tid] + fsig_(gi) * ftanh_(gg);
        const float h = fsig_(go) * ftanh_(c);
        lds_c[tid] = c;
        const int col = wg * 16 + tid;
        __hip_atomic_store((u32*)&s0[(size_t)t * HID + col], __float_as_uint(h),
                           __ATOMIC_RELAXED, __HIP_MEMORY_SCOPE_AGENT);
        if (t == T - 1) {
          if (hf0) hf0[col] = h;
          if (cf0) cf0[col] = c;
        }
        asm volatile("s_waitcnt vmcnt(0)" ::: "memory");   // data visible before tag
        if (tid == 0)
          __hip_atomic_store(&t0[(size_t)t * 64 + wg], (u32)(t + 1),
                             __ATOMIC_RELAXED, __HIP_MEMORY_SCOPE_AGENT);
      }
      // no trailing barrier: next iteration's post-staging barrier orders reuse
    }
  } else {
    // ================= layer 1: 8 units/WG, 16 lanes/row, fused Wi+Wh ====
    const int wg1 = wg - 64;              // 0..127
    const int lane16 = tid & 15;
    const int rloc = tid >> 4;            // 0..31
    const int jloc = rloc & 7;
    const int gate = rloc >> 3;
    const int grow = gate * HID + wg1 * 8 + jloc;

    float4 Wir[16], Whr[16];
    {
      const float4* wi = (const float4*)(Wi1 + (size_t)grow * HID);
      const float4* wh = (const float4*)(Wh1 + (size_t)grow * HID);
#pragma unroll
      for (int i = 0; i < 16; ++i) {
        Wir[i] = wi[lane16 + i * 16];
        Whr[i] = wh[lane16 + i * 16];
      }
    }
    const float breg = bi1[grow] + bh1[grow];

    if (tid < 8) lds_c[tid] = c01[wg1 * 8 + tid];
    if (tid < 256) ((float4*)lds_h)[tid] = ((const float4*)h01)[tid];
    __syncthreads();

    for (int t = 0; t < T; ++t) {
      if (tid < 256) {
        // x = layer-0 h at step t (tag value t+1)
        const int c4 = tid << 2;
        const u32* tg = t0 + (size_t)t * 64 + (c4 >> 4);
        while (__hip_atomic_load(tg, __ATOMIC_RELAXED, __HIP_MEMORY_SCOPE_AGENT) < (u32)(t + 1)) {}
        const float4 v = load_coherent4(s0 + (size_t)t * HID + c4);
        *(float4*)&lds_x[c4] = v;
      } else if (t > 0) {
        // h = own-layer h at step t-1 (tag value t)
        const int u = tid - 256;
        const int c4 = u << 2;
        const u32* tg = t1 + (size_t)(t - 1) * 128 + (u >> 1);
        while (__hip_atomic_load(tg, __ATOMIC_RELAXED, __HIP_MEMORY_SCOPE_AGENT) < (u32)t) {}
        const float4 v = load_coherent4(s1 + (size_t)(t - 1) * HID + c4);
        *(float4*)&lds_h[c4] = v;
      }
      __syncthreads();

      float p0 = 0.f, p1 = 0.f, p2 = 0.f, p3 = 0.f;
#pragma unroll
      for (int i = 0; i < 16; ++i) {
        const float4 hv = *(const float4*)&lds_h[(lane16 << 2) + (i << 6)];
        p0 = fmaf(Whr[i].x, hv.x, p0);
        p1 = fmaf(Whr[i].y, hv.y, p1);
        p2 = fmaf(Whr[i].z, hv.z, p2);
        p3 = fmaf(Whr[i].w, hv.w, p3);
      }
#pragma unroll
      for (int i = 0; i < 16; ++i) {
        const float4 xv = *(const float4*)&lds_x[(lane16 << 2) + (i << 6)];
        p0 = fmaf(Wir[i].x, xv.x, p0);
        p1 = fmaf(Wir[i].y, xv.y, p1);
        p2 = fmaf(Wir[i].z, xv.z, p2);
        p3 = fmaf(Wir[i].w, xv.w, p3);
      }
      float sum = (p0 + p1) + (p2 + p3);
      sum += __shfl_xor(sum, 1);
      sum += __shfl_xor(sum, 2);
      sum += __shfl_xor(sum, 4);
      sum += __shfl_xor(sum, 8);
      if (lane16 == 0) lds_g[rloc] = sum + breg;
      __syncthreads();

      if (tid < 8) {
        const float gi = lds_g[tid];
        const float gf = lds_g[8 + tid];
        const float gg = lds_g[16 + tid];
        const float go = lds_g[24 + tid];
        const float c = fsig_(gf) * lds_c[tid] + fsig_(gi) * ftanh_(gg);
        const float h = fsig_(go) * ftanh_(c);
        lds_c[tid] = c;
        const int col = wg1 * 8 + tid;
        __hip_atomic_store((u32*)&s1[(size_t)t * HID + col], __float_as_uint(h),
                           __ATOMIC_RELAXED, __HIP_MEMORY_SCOPE_AGENT);
        if (dec_out) dec_out[(size_t)t * HID + col] = h;
        if (t == T - 1) {
          if (hf1) hf1[col] = h;
          if (cf1) cf1[col] = c;
        }
        asm volatile("s_waitcnt vmcnt(0)" ::: "memory");   // data visible before tag
        if (tid == 0)
          __hip_atomic_store(&t1[(size_t)t * 128 + wg1], (u32)(t + 1),
                             __ATOMIC_RELAXED, __HIP_MEMORY_SCOPE_AGENT);
      }
    }
  }
}

// ---------------- launch ----------------
extern "C" void kernel_launch(void* const* d_in, const int* in_sizes, int n_in,
                              void* d_out, int out_size, void* d_ws, size_t ws_size,
                              hipStream_t stream) {
  const int*   inputs  = (const int*)d_in[0];
  const int*   outputs = (const int*)d_in[1];
  const int*   sos     = (const int*)d_in[2];
  const float* enc_emb = (const float*)d_in[3];
  const float* dec_emb = (const float*)d_in[4];
  const float* enc_Wih = (const float*)d_in[5];
  const float* enc_Whh = (const float*)d_in[6];
  const float* enc_bih = (const float*)d_in[7];
  const float* enc_bhh = (const float*)d_in[8];
  const float* dec_Wih = (const float*)d_in[9];
  const float* dec_Whh = (const float*)d_in[10];
  const float* dec_bih = (const float*)d_in[11];
  const float* dec_bhh = (const float*)d_in[12];
  const float* lin_W   = (const float*)d_in[13];
  const float* lin_b   = (const float*)d_in[14];

  float* out = (float*)d_out;
  // d_out scratch carve (all dead before the logits GEMM writes):
  float* A_enc = out;                     // 8M floats (32 MB)
  float* A_dec = out + 8388608;           // 8M floats
  float* s0e   = out + 16777216;          // 2M floats each stream
  float* s1e   = s0e + 2097152;
  float* s0d   = s1e + 2097152;
  float* s1d   = s0d + 2097152;
  u32*   tagsB = (u32*)(out + 25165824);  // 786432 u32 = 3 MB
  u32*   t0e = tagsB;                     // [2048][64]
  u32*   t1e = t0e + 2048 * 64;           // [2048][128]
  u32*   t0d = t1e + 2048 * 128;          // [2048][64]
  u32*   t1d = t0d + 2048 * 64;           // [2048][128]
  const int NTAGS = 2048 * 384;

  char* ws = (char*)d_ws;
  float* zerosv = (float*)(ws + 0);       // 1024 zeros
  float* hf0    = (float*)(ws + 4096);
  float* cf0    = (float*)(ws + 8192);
  float* hf1    = (float*)(ws + 12288);
  float* cf1    = (float*)(ws + 16384);
  int*   dtoks  = (int*)(ws + 20480);     // 2048 decoder tokens
  float* B1 = (float*)(ws + ((size_t)1  << 20));  // 8 MB: enc embeddings
  float* B3 = (float*)(ws + ((size_t)10 << 20));  // 8 MB: dec embeddings
  float* B2 = (float*)(ws + ((size_t)19 << 20));  // 8 MB: dec_out (logits GEMM X)

  const size_t WOFF = (size_t)GATES * HID;  // layer stride in Wih/Whh
  const dim3 gemm_blk(256);
  const dim3 gemmA_grid(GATES / 64, S_LEN / 64);
  const dim3 gemmV_grid((VOCAB + 63) / 64, T_LEN / 64);

  // zero tag arrays (every launch: write-once protocol) + zeros vector
  zero_u32<<<(NTAGS + 255) / 256, 256, 0, stream>>>(tagsB, NTAGS);
  zero_u32<<<4, 256, 0, stream>>>((u32*)zerosv, 1024);
  build_dec_tokens<<<8, 256, 0, stream>>>(outputs, sos, dtoks, T_LEN);

  // embeddings + layer-0 preactivation GEMMs (both precomputable: teacher forcing)
  gather_rows<<<S_LEN, 256, 0, stream>>>(enc_emb, inputs, B1);
  gemm_xwt<<<gemmA_grid, gemm_blk, 0, stream>>>(B1, enc_Wih, enc_bih, enc_bhh, A_enc, S_LEN, GATES, HID);
  gather_rows<<<T_LEN, 256, 0, stream>>>(dec_emb, dtoks, B3);
  gemm_xwt<<<gemmA_grid, gemm_blk, 0, stream>>>(B3, dec_Wih, dec_bih, dec_bhh, A_dec, T_LEN, GATES, HID);

  // encoder: both layers pipelined in one kernel
  lstm2<<<NWG2, RECT, 0, stream>>>(
      A_enc, enc_Whh, enc_Wih + WOFF, enc_Whh + WOFF, enc_bih + GATES, enc_bhh + GATES,
      zerosv, zerosv, zerosv, zerosv, s0e, s1e, t0e, t1e, hf0, cf0, hf1, cf1, nullptr, S_LEN);

  // decoder: both layers pipelined; layer-1 h also written plain to B2
  lstm2<<<NWG2, RECT, 0, stream>>>(
      A_dec, dec_Whh, dec_Wih + WOFF, dec_Whh + WOFF, dec_bih + GATES, dec_bhh + GATES,
      hf0, cf0, hf1, cf1, s0d, s1d, t0d, t1d, nullptr, nullptr, nullptr, nullptr, B2, T_LEN);

  // logits
  gemm_xwt<<<gemmV_grid, gemm_blk, 0, stream>>>(B2, lin_W, lin_b, nullptr, out, T_LEN, VOCAB, HID);
}

// Round 5
// 15796.539 us; speedup vs baseline: 1.6539x; 1.6539x over previous
//
#include <hip/hip_runtime.h>
#include <hip/hip_bf16.h>
#include <math.h>

// ---------------- problem constants ----------------
#define S_LEN 2048
#define T_LEN 2048
#define HID   1024
#define GATES 4096
#define VOCAB 50257

typedef unsigned int u32;
typedef unsigned long long ull;
typedef u32 u32x4 __attribute__((ext_vector_type(4)));

__device__ __forceinline__ float fsig_(float x)  { return 1.0f / (1.0f + __expf(-x)); }
__device__ __forceinline__ float ftanh_(float x) { float e = __expf(2.0f * x); return 1.0f - 2.0f / (e + 1.0f); }

// coherent 16B load (bypasses non-coherent per-XCD L1/L2): two packed {tag,h} slots
__device__ __forceinline__ u32x4 cload16(const ull* p) {
  u32x4 v;
  asm volatile("global_load_dwordx4 %0, %1, off sc0 sc1\n\ts_waitcnt vmcnt(0)"
               : "=v"(v) : "v"(p) : "memory");
  return v;
}

// ---------------- tiny helpers ----------------
__global__ void zero_f4(float4* __restrict__ p, size_t n4) {
  size_t i = (size_t)blockIdx.x * blockDim.x + threadIdx.x;
  size_t stride = (size_t)gridDim.x * blockDim.x;
  for (; i < n4; i += stride) p[i] = make_float4(0.f, 0.f, 0.f, 0.f);
}

__global__ void zero_u32(u32* __restrict__ p, int n) {
  int i = blockIdx.x * blockDim.x + threadIdx.x;
  if (i < n) p[i] = 0u;
}

__global__ void build_dec_tokens(const int* __restrict__ outputs, const int* __restrict__ sos,
                                 int* __restrict__ toks, int T) {
  int t = blockIdx.x * blockDim.x + threadIdx.x;
  if (t < T) toks[t] = (t == 0) ? sos[0] : outputs[t - 1];
}

// ---------------- f32 GEMM: C[M][N] = X[M][K] @ W[N][K]^T + b1 ----------------
// 64x64 tile, 256 threads, 4x4 microtile, BK=16
__global__ __launch_bounds__(256) void gemm_xwt(
    const float* __restrict__ X, const float* __restrict__ W,
    const float* __restrict__ b1,
    float* __restrict__ C, int M, int N, int K)
{
  __shared__ float Xs[16][68];
  __shared__ float Ws[16][68];
  const int tid = threadIdx.x;
  const int tx = tid & 15;
  const int ty = tid >> 4;
  const int m0 = blockIdx.y * 64;
  const int n0 = blockIdx.x * 64;
  const int lr = tid >> 2;
  const int lc = (tid & 3) * 4;
  float acc[4][4] = {{0.f}};

  for (int k0 = 0; k0 < K; k0 += 16) {
    float4 xv = *(const float4*)(X + (size_t)(m0 + lr) * K + k0 + lc);
    float4 wv = make_float4(0.f, 0.f, 0.f, 0.f);
    int wr = n0 + lr;
    if (wr < N) wv = *(const float4*)(W + (size_t)wr * K + k0 + lc);
    __syncthreads();
    Xs[lc + 0][lr] = xv.x; Xs[lc + 1][lr] = xv.y; Xs[lc + 2][lr] = xv.z; Xs[lc + 3][lr] = xv.w;
    Ws[lc + 0][lr] = wv.x; Ws[lc + 1][lr] = wv.y; Ws[lc + 2][lr] = wv.z; Ws[lc + 3][lr] = wv.w;
    __syncthreads();
#pragma unroll
    for (int kk = 0; kk < 16; ++kk) {
      float4 a = *(const float4*)&Xs[kk][ty * 4];
      float4 b = *(const float4*)&Ws[kk][tx * 4];
      float av[4] = {a.x, a.y, a.z, a.w};
      float bv[4] = {b.x, b.y, b.z, b.w};
#pragma unroll
      for (int i = 0; i < 4; ++i)
#pragma unroll
        for (int j = 0; j < 4; ++j)
          acc[i][j] = fmaf(av[i], bv[j], acc[i][j]);
    }
  }
#pragma unroll
  for (int i = 0; i < 4; ++i) {
    int m = m0 + ty * 4 + i;
#pragma unroll
    for (int j = 0; j < 4; ++j) {
      int n = n0 + tx * 4 + j;
      if (n < N) C[(size_t)m * N + n] = acc[i][j] + (b1 ? b1[n] : 0.f);
    }
  }
}

// ---------------- fused 2-layer persistent LSTM, layer-pipelined ----------------
// 256 WGs x 512 threads: wg<128 = layer 0 (x from embedding rows, prefetched),
// wg>=128 = layer 1 (x = layer-0 h at step t, 1-step skew). BOTH layers fuse
// Wi@x + Wh@h with register-resident weight rows (no precomputed A, no GEMMs):
// 8 units/WG, 32 gate rows, 16 lanes/row, 128 MACs/thread (32 float4 weights).
// Exchange: write-once streams of packed 8B slots {tag=t+1 (hi32), h (lo32)},
// relaxed agent-scope stores (R3-proven: data+flag in ONE word = 1 store RT +
// 1 poll RT; R4 proved splitting them costs 2 extra serialized RTs).
// Consumers poll TWO adjacent slots with one 16B coherent load; per-8B tags
// make torn halves detectable (re-poll), so no write-atomicity is needed.
__global__ __launch_bounds__(512, 2) void lstm2(
    const float* __restrict__ emb,  const int* __restrict__ toks,
    const float* __restrict__ Wi0,  const float* __restrict__ Wh0,
    const float* __restrict__ bi0,  const float* __restrict__ bh0,
    const float* __restrict__ Wi1,  const float* __restrict__ Wh1,
    const float* __restrict__ bi1,  const float* __restrict__ bh1,
    const float* __restrict__ h00,  const float* __restrict__ c00,
    const float* __restrict__ h01,  const float* __restrict__ c01,
    ull* __restrict__ s0, ull* __restrict__ s1,
    float* __restrict__ hf0, float* __restrict__ cf0,
    float* __restrict__ hf1, float* __restrict__ cf1,
    float* __restrict__ dec_out, int T)
{
  const int tid = threadIdx.x;
  const int wg  = blockIdx.x;
  const bool isL0 = (wg < 128);
  const int wgl = isL0 ? wg : wg - 128;

  const int lane16 = tid & 15;
  const int rloc = tid >> 4;            // 0..31 local gate row
  const int jloc = rloc & 7;            // unit within WG
  const int gate = rloc >> 3;           // 0=i 1=f 2=g 3=o
  const int grow = gate * HID + wgl * 8 + jloc;

  __shared__ float lds_x[2][HID];
  __shared__ float lds_h[HID];
  __shared__ float lds_g[32];
  __shared__ float lds_c[8];

  const float* Wi = isL0 ? Wi0 : Wi1;
  const float* Wh = isL0 ? Wh0 : Wh1;
  const float breg = (isL0 ? (bi0[grow] + bh0[grow]) : (bi1[grow] + bh1[grow]));

  // weight rows -> registers: col block 4*(lane16 + 16*i)
  float4 Wir[16], Whr[16];
  {
    const float4* wi = (const float4*)(Wi + (size_t)grow * HID);
    const float4* wh = (const float4*)(Wh + (size_t)grow * HID);
#pragma unroll
    for (int i = 0; i < 16; ++i) {
      Wir[i] = wi[lane16 + i * 16];
      Whr[i] = wh[lane16 + i * 16];
    }
  }

  {
    const float* hini = isL0 ? h00 : h01;
    const float* cini = isL0 ? c00 : c01;
    if (tid < 8) lds_c[tid] = cini[wgl * 8 + tid];
    if (tid < 256) ((float4*)lds_h)[tid] = ((const float4*)hini)[tid];
    if (isL0 && tid < 256) {           // stage x_0
      int tok = toks[0];
      ((float4*)lds_x[0])[tid] = ((const float4*)(emb + (size_t)tok * HID))[tid];
    }
  }
  __syncthreads();

  ull* s_mine = isL0 ? s0 : s1;

  for (int t = 0; t < T; ++t) {
    const int cur = t & 1;

    // ---- stage inputs for this step (polls on the critical path) ----
    if (isL0) {
      if (t > 0) {
        const ull* ph = s0 + (size_t)(t - 1) * HID + 2 * tid;
        u32x4 v = cload16(ph);
        while (v.y < (u32)t || v.w < (u32)t) v = cload16(ph);
        lds_h[2 * tid]     = __uint_as_float(v.x);
        lds_h[2 * tid + 1] = __uint_as_float(v.z);
      }
    } else {
      const ull* px = s0 + (size_t)t * HID + 2 * tid;
      u32x4 vx = cload16(px);
      while (vx.y < (u32)(t + 1) || vx.w < (u32)(t + 1)) vx = cload16(px);
      lds_x[0][2 * tid]     = __uint_as_float(vx.x);
      lds_x[0][2 * tid + 1] = __uint_as_float(vx.z);
      if (t > 0) {
        const ull* ph = s1 + (size_t)(t - 1) * HID + 2 * tid;
        u32x4 v = cload16(ph);
        while (v.y < (u32)t || v.w < (u32)t) v = cload16(ph);
        lds_h[2 * tid]     = __uint_as_float(v.x);
        lds_h[2 * tid + 1] = __uint_as_float(v.z);
      }
    }
    __syncthreads();

    // L0: prefetch x_{t+1} AFTER the poll barrier so its vmem retire hides
    // under this step's compute instead of inside next step's poll vmcnt(0).
    if (isL0 && tid < 256 && t + 1 < T) {
      int tok = toks[t + 1];
      ((float4*)lds_x[cur ^ 1])[tid] = ((const float4*)(emb + (size_t)tok * HID))[tid];
    }

    // ---- fused gate dot: Wi@x + Wh@h, 128 MACs/thread ----
    const float* xbuf = isL0 ? lds_x[cur] : lds_x[0];
    float p0 = 0.f, p1 = 0.f, p2 = 0.f, p3 = 0.f;
#pragma unroll
    for (int i = 0; i < 16; ++i) {
      const float4 xv = *(const float4*)&xbuf[(lane16 << 2) + (i << 6)];
      p0 = fmaf(Wir[i].x, xv.x, p0);
      p1 = fmaf(Wir[i].y, xv.y, p1);
      p2 = fmaf(Wir[i].z, xv.z, p2);
      p3 = fmaf(Wir[i].w, xv.w, p3);
    }
#pragma unroll
    for (int i = 0; i < 16; ++i) {
      const float4 hv = *(const float4*)&lds_h[(lane16 << 2) + (i << 6)];
      p0 = fmaf(Whr[i].x, hv.x, p0);
      p1 = fmaf(Whr[i].y, hv.y, p1);
      p2 = fmaf(Whr[i].z, hv.z, p2);
      p3 = fmaf(Whr[i].w, hv.w, p3);
    }
    float sum = (p0 + p1) + (p2 + p3);
    sum += __shfl_xor(sum, 1);
    sum += __shfl_xor(sum, 2);
    sum += __shfl_xor(sum, 4);
    sum += __shfl_xor(sum, 8);
    if (lane16 == 0) lds_g[rloc] = sum + breg;
    __syncthreads();

    // ---- gate epilogue + packed publish ----
    if (tid < 8) {
      const float gi = lds_g[tid];
      const float gf = lds_g[8 + tid];
      const float gg = lds_g[16 + tid];
      const float go = lds_g[24 + tid];
      const float c = fsig_(gf) * lds_c[tid] + fsig_(gi) * ftanh_(gg);
      const float h = fsig_(go) * ftanh_(c);
      lds_c[tid] = c;
      const int col = wgl * 8 + tid;
      const ull pk = ((ull)(u32)(t + 1) << 32) | (ull)__float_as_uint(h);
      __hip_atomic_store(&s_mine[(size_t)t * HID + col], pk,
                         __ATOMIC_RELAXED, __HIP_MEMORY_SCOPE_AGENT);
      if (!isL0 && dec_out) dec_out[(size_t)t * HID + col] = h;
      if (t == T - 1) {
        if (isL0) { if (hf0) hf0[col] = h; if (cf0) cf0[col] = c; }
        else      { if (hf1) hf1[col] = h; if (cf1) cf1[col] = c; }
      }
    }
    // no trailing barrier: next step's post-poll barrier orders LDS reuse
  }
}

// ---------------- launch ----------------
extern "C" void kernel_launch(void* const* d_in, const int* in_sizes, int n_in,
                              void* d_out, int out_size, void* d_ws, size_t ws_size,
                              hipStream_t stream) {
  const int*   inputs  = (const int*)d_in[0];
  const int*   outputs = (const int*)d_in[1];
  const int*   sos     = (const int*)d_in[2];
  const float* enc_emb = (const float*)d_in[3];
  const float* dec_emb = (const float*)d_in[4];
  const float* enc_Wih = (const float*)d_in[5];
  const float* enc_Whh = (const float*)d_in[6];
  const float* enc_bih = (const float*)d_in[7];
  const float* enc_bhh = (const float*)d_in[8];
  const float* dec_Wih = (const float*)d_in[9];
  const float* dec_Whh = (const float*)d_in[10];
  const float* dec_bih = (const float*)d_in[11];
  const float* dec_bhh = (const float*)d_in[12];
  const float* lin_W   = (const float*)d_in[13];
  const float* lin_b   = (const float*)d_in[14];

  float* out = (float*)d_out;
  // d_out scratch carve: 4 packed streams (16 MB each), all dead before logits.
  ull* s0e = (ull*)d_out;
  ull* s1e = s0e + 2097152;
  ull* s0d = s1e + 2097152;
  ull* s1d = s0d + 2097152;

  char* ws = (char*)d_ws;
  float* zerosv = (float*)(ws + 0);
  float* hf0    = (float*)(ws + 4096);
  float* cf0    = (float*)(ws + 8192);
  float* hf1    = (float*)(ws + 12288);
  float* cf1    = (float*)(ws + 16384);
  int*   dtoks  = (int*)(ws + 20480);
  float* B2     = (float*)(ws + ((size_t)1 << 20));   // 8 MB: dec_out (logits X)

  const size_t WOFF = (size_t)GATES * HID;

  // zero stream tags (64 MB in d_out) + zeros vector; rebuild tokens each call
  zero_f4<<<2048, 256, 0, stream>>>((float4*)d_out, 4194304);
  zero_u32<<<4, 256, 0, stream>>>((u32*)zerosv, 1024);
  build_dec_tokens<<<8, 256, 0, stream>>>(outputs, sos, dtoks, T_LEN);

  // encoder: both layers, fused Wi@x, layer-pipelined
  lstm2<<<256, 512, 0, stream>>>(
      enc_emb, inputs,
      enc_Wih, enc_Whh, enc_bih, enc_bhh,
      enc_Wih + WOFF, enc_Whh + WOFF, enc_bih + GATES, enc_bhh + GATES,
      zerosv, zerosv, zerosv, zerosv,
      s0e, s1e, hf0, cf0, hf1, cf1, nullptr, S_LEN);

  // decoder: init from encoder finals; layer-1 h also written plain to B2
  lstm2<<<256, 512, 0, stream>>>(
      dec_emb, dtoks,
      dec_Wih, dec_Whh, dec_bih, dec_bhh,
      dec_Wih + WOFF, dec_Whh + WOFF, dec_bih + GATES, dec_bhh + GATES,
      hf0, cf0, hf1, cf1,
      s0d, s1d, nullptr, nullptr, nullptr, nullptr, B2, T_LEN);

  // logits
  dim3 gemmV_grid((VOCAB + 63) / 64, T_LEN / 64);
  gemm_xwt<<<gemmV_grid, 256, 0, stream>>>(B2, lin_W, lin_b, out, T_LEN, VOCAB, HID);
}